// Round 1
// baseline (15090.622 us; speedup 1.0000x reference)
//
#include <hip/hip_runtime.h>

// ---------------------------------------------------------------------------
// SubtasksRecurrence: T=128 sequential steps, B=256 independent rows.
// Precompute (parallel): sxb = obs@W_f_x^T + b_f  (f32 GEMM, 69 GFLOP)
//                        bx  = obs@W_beta_x^T + b_beta
//                        gumbel tables via bit-exact threefry2x32 (JAX partitionable scheme)
// Sequential: 256 blocks (1 per row) with device-scope grid barrier, 3 phases/step.
// All math f32 to keep categorical argmax decisions identical to the JAX/np reference.
// ---------------------------------------------------------------------------

#define RNG_PARTITIONABLE 1

#define T_STEPS 128
#define B_ROWS  256
#define H_DIM   256
#define N_DIM   16
#define S_DIM   32
#define TOT     338
#define CONV    4096
#define LDWF    4161   // W_f row stride (CONV + 2S + 1)
#define LDWB    4128   // W_beta row stride (CONV + S)

// ------------------------------- threefry ----------------------------------
__device__ __forceinline__ void tf2x32(unsigned k0, unsigned k1, unsigned c0, unsigned c1,
                                       unsigned &o0, unsigned &o1) {
  const unsigned ks2 = k0 ^ k1 ^ 0x1BD11BDAu;
  unsigned x0 = c0 + k0;
  unsigned x1 = c1 + k1;
#define TFR(r) { x0 += x1; x1 = (x1 << (r)) | (x1 >> (32 - (r))); x1 ^= x0; }
  TFR(13) TFR(15) TFR(26) TFR(6)
  x0 += k1; x1 += ks2 + 1u;
  TFR(17) TFR(29) TFR(16) TFR(24)
  x0 += ks2; x1 += k0 + 2u;
  TFR(13) TFR(15) TFR(26) TFR(6)
  x0 += k0; x1 += k1 + 3u;
  TFR(17) TFR(29) TFR(16) TFR(24)
  x0 += k1; x1 += ks2 + 4u;
  TFR(13) TFR(15) TFR(26) TFR(6)
  x0 += ks2; x1 += k0 + 5u;
#undef TFR
  o0 = x0; o1 = x1;
}

// key j of jax.random.split(jax.random.key(42), 256)
__device__ __forceinline__ void rng_key(unsigned j, unsigned &k0, unsigned &k1) {
#if RNG_PARTITIONABLE
  tf2x32(0u, 42u, 0u, j, k0, k1);
#else
  // original split: counts=iota(512), halves (x0=i, x1=256+i), out=concat(o0,o1),
  // reshape (256,2): key_j = (flat[2j], flat[2j+1])
  unsigned w[2];
  for (int q = 0; q < 2; ++q) {
    unsigned i = 2u*j + (unsigned)q, a, b;
    if (i < 256u) { tf2x32(0u, 42u, i, 256u + i, a, b); w[q] = a; }
    else          { tf2x32(0u, 42u, i - 256u, i, a, b); w[q] = b; }
  }
  k0 = w[0]; k1 = w[1];
#endif
}

// 32-bit random bits for element idx of an array with `total` elements
__device__ __forceinline__ unsigned rng_bits(unsigned k0, unsigned k1, unsigned idx, unsigned total) {
#if RNG_PARTITIONABLE
  unsigned o0, o1;
  tf2x32(k0, k1, 0u, idx, o0, o1);
  return o0 ^ o1;
#else
  unsigned half = total >> 1, o0, o1;
  if (idx < half) { tf2x32(k0, k1, idx, half + idx, o0, o1); return o0; }
  else            { tf2x32(k0, k1, idx - half, idx, o0, o1); return o1; }
#endif
}

__device__ __forceinline__ float gumbel_from_bits(unsigned bits) {
  float u0 = __uint_as_float(0x3f800000u | (bits >> 9)) - 1.0f;  // [0,1)
  float u  = fmaxf(u0, 1.17549435e-38f);                          // minval=tiny clamp (exact JAX semantics)
  return -logf(-logf(u));
}

// ------------------------------ small kernels ------------------------------
__global__ __launch_bounds__(256) void rng_k(float* __restrict__ ggum, float* __restrict__ bgum) {
  unsigned tid = blockIdx.x * 256u + threadIdx.x;
  const unsigned NG = T_STEPS * B_ROWS * N_DIM;  // 524288
  const unsigned NB = T_STEPS * B_ROWS * 2;      // 65536
  if (tid < NG) {
    unsigned t = tid / (B_ROWS * N_DIM);
    unsigned i = tid % (B_ROWS * N_DIM);
    unsigned k0, k1; rng_key(2u * t, k0, k1);
    ggum[tid] = gumbel_from_bits(rng_bits(k0, k1, i, B_ROWS * N_DIM));
  } else if (tid < NG + NB) {
    unsigned q = tid - NG;
    unsigned t = q / (B_ROWS * 2);
    unsigned i = q % (B_ROWS * 2);
    unsigned k0, k1; rng_key(2u * t + 1u, k0, k1);
    bgum[q] = gumbel_from_bits(rng_bits(k0, k1, i, B_ROWS * 2));
  }
}

__global__ __launch_bounds__(256) void prep_k(const float* __restrict__ W_pi, float* __restrict__ wpiT) {
  int tid = blockIdx.x * 256 + threadIdx.x;
  if (tid < 288 * 16) {
    int k = tid / 16, o = tid % 16;
    wpiT[k * 16 + o] = W_pi[o * 288 + k];
  }
}

__global__ __launch_bounds__(256) void init_k(const float* __restrict__ hx0,
                                              float* __restrict__ hT0, float* __restrict__ rT,
                                              float* __restrict__ gT, float* __restrict__ brow) {
  int tid = blockIdx.x * 256 + threadIdx.x;
  if (tid < 65536) {
    int k = tid >> 8, b = tid & 255;
    hT0[k * 256 + b] = hx0[b * TOT + 48 + k];
  } else if (tid < 65536 + 8192) {
    int q = tid - 65536; int j = q >> 8, b = q & 255;
    rT[j * 256 + b] = hx0[b * TOT + 16 + j];
  } else if (tid < 65536 + 16384) {
    int q = tid - 65536 - 8192; int j = q >> 8, b = q & 255;
    gT[j * 256 + b] = hx0[b * TOT + 304 + j];
  } else if (tid < 65536 + 16384 + 256) {
    int b = tid - 65536 - 16384;
    brow[b] = hx0[b * TOT + 336];
  }
}

// bx[m][2] = obs_row . W_beta_x^T + b_beta  (memory-bound re-read of obs)
__device__ __forceinline__ float waveRed(float v) {
  v += __shfl_down(v, 32, 64);
  v += __shfl_down(v, 16, 64);
  v += __shfl_down(v, 8, 64);
  v += __shfl_down(v, 4, 64);
  v += __shfl_down(v, 2, 64);
  v += __shfl_down(v, 1, 64);
  return v;
}

__global__ __launch_bounds__(256) void bx_k(const float* __restrict__ obs,
                                            const float* __restrict__ W_beta,
                                            const float* __restrict__ b_beta,
                                            float* __restrict__ bxv) {
  int m = blockIdx.x, tid = threadIdx.x;
  const float* row = obs + (size_t)m * CONV;
  float p0 = 0.f, p1 = 0.f;
  for (int i = tid; i < CONV; i += 256) {
    float o = row[i];
    p0 = fmaf(o, W_beta[i], p0);
    p1 = fmaf(o, W_beta[LDWB + i], p1);
  }
  p0 = waveRed(p0); p1 = waveRed(p1);
  __shared__ float sc[2][4];
  int w = tid >> 6;
  if ((tid & 63) == 0) { sc[0][w] = p0; sc[1][w] = p1; }
  __syncthreads();
  if (tid == 0) bxv[(size_t)m * 2 + 0] = sc[0][0] + sc[0][1] + sc[0][2] + sc[0][3] + b_beta[0];
  if (tid == 1) bxv[(size_t)m * 2 + 1] = sc[1][0] + sc[1][1] + sc[1][2] + sc[1][3] + b_beta[1];
}

// ------------------------------- big GEMM ----------------------------------
// C1T[t][n][b] = obs[m=t*256+b] . W_f[n][:4096] + b_f[n]   (M=32768, N=256, K=4096)
struct __attribute__((packed, aligned(4))) F4 { float x, y, z, w; };

__global__ __launch_bounds__(256) void gemm1_k(const float* __restrict__ A,
                                               const float* __restrict__ W,
                                               const float* __restrict__ bias,
                                               float* __restrict__ C1T) {
  __shared__ __align__(16) float As[32][68];
  __shared__ __align__(16) float Bs[32][68];
  int bid = blockIdx.x;
  int mt = bid & 511, nt = bid >> 9;
  int m0 = mt * 64, n0 = nt * 64;
  int tid = threadIdx.x;
  int tm = tid & 15, tn = tid >> 4;
  int lr = tid >> 2;
  int lc = (tid & 3) * 8;
  float acc[4][4] = {};
  for (int k0 = 0; k0 < CONV; k0 += 32) {
    F4 a0 = *(const F4*)(A + (size_t)(m0 + lr) * CONV + k0 + lc);
    F4 a1 = *(const F4*)(A + (size_t)(m0 + lr) * CONV + k0 + lc + 4);
    F4 b0 = *(const F4*)(W + (size_t)(n0 + lr) * LDWF + k0 + lc);
    F4 b1 = *(const F4*)(W + (size_t)(n0 + lr) * LDWF + k0 + lc + 4);
    __syncthreads();
    As[lc + 0][lr] = a0.x; As[lc + 1][lr] = a0.y; As[lc + 2][lr] = a0.z; As[lc + 3][lr] = a0.w;
    As[lc + 4][lr] = a1.x; As[lc + 5][lr] = a1.y; As[lc + 6][lr] = a1.z; As[lc + 7][lr] = a1.w;
    Bs[lc + 0][lr] = b0.x; Bs[lc + 1][lr] = b0.y; Bs[lc + 2][lr] = b0.z; Bs[lc + 3][lr] = b0.w;
    Bs[lc + 4][lr] = b1.x; Bs[lc + 5][lr] = b1.y; Bs[lc + 6][lr] = b1.z; Bs[lc + 7][lr] = b1.w;
    __syncthreads();
#pragma unroll
    for (int kk = 0; kk < 32; ++kk) {
      const float4 av = *(const float4*)&As[kk][tm * 4];
      const float4 bv = *(const float4*)&Bs[kk][tn * 4];
      acc[0][0] = fmaf(av.x, bv.x, acc[0][0]); acc[0][1] = fmaf(av.x, bv.y, acc[0][1]);
      acc[0][2] = fmaf(av.x, bv.z, acc[0][2]); acc[0][3] = fmaf(av.x, bv.w, acc[0][3]);
      acc[1][0] = fmaf(av.y, bv.x, acc[1][0]); acc[1][1] = fmaf(av.y, bv.y, acc[1][1]);
      acc[1][2] = fmaf(av.y, bv.z, acc[1][2]); acc[1][3] = fmaf(av.y, bv.w, acc[1][3]);
      acc[2][0] = fmaf(av.z, bv.x, acc[2][0]); acc[2][1] = fmaf(av.z, bv.y, acc[2][1]);
      acc[2][2] = fmaf(av.z, bv.z, acc[2][2]); acc[2][3] = fmaf(av.z, bv.w, acc[2][3]);
      acc[3][0] = fmaf(av.w, bv.x, acc[3][0]); acc[3][1] = fmaf(av.w, bv.y, acc[3][1]);
      acc[3][2] = fmaf(av.w, bv.z, acc[3][2]); acc[3][3] = fmaf(av.w, bv.w, acc[3][3]);
    }
  }
  const int t = m0 >> 8;
  const int bb0 = (m0 & 255) + tm * 4;
  const int nn0 = n0 + tn * 4;
  float* cbase = C1T + (size_t)t * 65536;
#pragma unroll
  for (int j = 0; j < 4; ++j) {
    float bv = bias[nn0 + j];
#pragma unroll
    for (int i = 0; i < 4; ++i)
      cbase[(nn0 + j) * 256 + bb0 + i] = acc[i][j] + bv;
  }
}

// ------------------------------ grid barrier -------------------------------
__device__ __forceinline__ void grid_sync(unsigned* cnt, unsigned* gen) {
  __syncthreads();
  if (threadIdx.x == 0) {
    unsigned g = __hip_atomic_load(gen, __ATOMIC_ACQUIRE, __HIP_MEMORY_SCOPE_AGENT);
    unsigned a = __hip_atomic_fetch_add(cnt, 1u, __ATOMIC_ACQ_REL, __HIP_MEMORY_SCOPE_AGENT);
    if (a == (unsigned)(B_ROWS - 1)) {
      __hip_atomic_store(cnt, 0u, __ATOMIC_RELAXED, __HIP_MEMORY_SCOPE_AGENT);
      __hip_atomic_fetch_add(gen, 1u, __ATOMIC_ACQ_REL, __HIP_MEMORY_SCOPE_AGENT);
    } else {
      while (__hip_atomic_load(gen, __ATOMIC_ACQUIRE, __HIP_MEMORY_SCOPE_AGENT) == g)
        __builtin_amdgcn_s_sleep(4);
    }
  }
  __syncthreads();
}

// ------------------------------ sequential ---------------------------------
__global__ __launch_bounds__(256) void seq_k(
    const float* __restrict__ hx0, const float* __restrict__ task,
    const float* __restrict__ W_f, const float* __restrict__ W_ih,
    const float* __restrict__ W_hh, const float* __restrict__ b_ih,
    const float* __restrict__ b_hh, const float* __restrict__ W_u,
    const float* __restrict__ b_u, const float* __restrict__ W_s,
    const float* __restrict__ b_s, const float* __restrict__ b_pi,
    const float* __restrict__ W_beta, const float* __restrict__ C1T,
    const float* __restrict__ bxv, const float* __restrict__ wpiT,
    const float* __restrict__ ggum, const float* __restrict__ bgum,
    float* __restrict__ hT, float* __restrict__ sT, float* __restrict__ hnT,
    float* __restrict__ rT, float* __restrict__ gT, float* __restrict__ brow,
    unsigned* __restrict__ bar, float* __restrict__ out) {
  const int b = blockIdx.x;   // this block owns row b ...
  const int n = b;            // ... and GRU column triple {n, n+256, n+512}
  const int tid = threadIdx.x;

  __shared__ float l_sh[3];
  __shared__ float ch_sh;
  __shared__ float c_sh;
  __shared__ float p_sh[16], pn_sh[16], r_sh[32], rn_sh[32], g_sh[32];
  __shared__ float hrow_sh[256];
  __shared__ float logit_sh[16];
  __shared__ float red4[4][4];
  __shared__ float red16[4][16];
  __shared__ int gidx_sh;
  __shared__ float misc_sh[4];  // 0: lp_g, 1: b', 2: lp_total

  if (tid < 16) p_sh[tid] = hx0[b * TOT + tid];
  if (tid < 32) {
    r_sh[tid] = hx0[b * TOT + 16 + tid];
    g_sh[tid] = hx0[b * TOT + 304 + tid];
  }
  __syncthreads();

  int cur = 0;
  for (int t = 0; t < T_STEPS; ++t) {
    const float* hTc = hT + (size_t)cur * 65536;
    float* hTn = hT + (size_t)(cur ^ 1) * 65536;

    // ---------------- Phase 1 ----------------
    // (i) row pass over old h column b: l logits + c h-part; keep h_old in reg
    float hk_old = hTc[tid * 256 + b];
    {
      float a0 = hk_old * W_s[tid];
      float a1 = hk_old * W_s[256 + tid];
      float a2 = hk_old * W_s[512 + tid];
      float a3 = hk_old * W_u[256 + tid];
      a0 = waveRed(a0); a1 = waveRed(a1); a2 = waveRed(a2); a3 = waveRed(a3);
      int w = tid >> 6;
      if ((tid & 63) == 0) { red4[w][0] = a0; red4[w][1] = a1; red4[w][2] = a2; red4[w][3] = a3; }
    }
    __syncthreads();
    if (tid == 0) {
      float x0 = red4[0][0] + red4[1][0] + red4[2][0] + red4[3][0] + b_s[0];
      float x1 = red4[0][1] + red4[1][1] + red4[2][1] + red4[3][1] + b_s[1];
      float x2 = red4[0][2] + red4[1][2] + red4[2][2] + red4[3][2] + b_s[2];
      float m = fmaxf(x0, fmaxf(x1, x2));
      float e0 = expf(x0 - m), e1 = expf(x1 - m), e2 = expf(x2 - m);
      float s = e0 + e1 + e2;
      l_sh[0] = e0 / s; l_sh[1] = e1 / s; l_sh[2] = e2 / s;
      ch_sh = red4[0][3] + red4[1][3] + red4[2][3] + red4[3][3];
    }
    // (ii) col pass: s column n, gh triple (kept in regs)
    float gh0, gh1, gh2;
    {
      float sacc = C1T[(size_t)t * 65536 + n * 256 + tid];
      const float* wfr = W_f + (size_t)n * LDWF + CONV;
#pragma unroll 8
      for (int j = 0; j < 32; ++j) sacc = fmaf(rT[j * 256 + tid], wfr[j], sacc);
#pragma unroll 8
      for (int j = 0; j < 32; ++j) sacc = fmaf(gT[j * 256 + tid], wfr[32 + j], sacc);
      sacc = fmaf(brow[tid], wfr[64], sacc);
      sT[n * 256 + tid] = sacc;

      const float* wh0 = W_hh + (size_t)n * 256;
      const float* wh1 = W_hh + (size_t)(n + 256) * 256;
      const float* wh2 = W_hh + (size_t)(n + 512) * 256;
      float g0 = 0.f, g1 = 0.f, g2 = 0.f;
#pragma unroll 4
      for (int k = 0; k < 256; ++k) {
        float hv = hTc[k * 256 + tid];
        g0 = fmaf(hv, wh0[k], g0);
        g1 = fmaf(hv, wh1[k], g1);
        g2 = fmaf(hv, wh2[k], g2);
      }
      gh0 = g0 + b_hh[n]; gh1 = g1 + b_hh[n + 256]; gh2 = g2 + b_hh[n + 512];
    }
    __syncthreads();
    // (iii) row: p_new, r_new (pre-gating)
    if (tid < 16) {
      float pm1 = (tid > 0) ? p_sh[tid - 1] : 0.f;
      float pp1 = (tid < 15) ? p_sh[tid + 1] : 0.f;
      pn_sh[tid] = l_sh[0] * pm1 + l_sh[1] * p_sh[tid] + l_sh[2] * pp1;
    }
    __syncthreads();
    if (tid < 32) {
      float acc = 0.f;
      const float* mrow = task + (size_t)b * 512 + tid;
#pragma unroll
      for (int n2 = 0; n2 < 16; ++n2) acc = fmaf(pn_sh[n2], mrow[n2 * 32], acc);
      rn_sh[tid] = acc;
    }
    grid_sync(bar, bar + 1);

    // ---------------- Phase 2 ----------------
    // col: gi triple over full s, GRU h_new (pre-c-gating)
    {
      const float* wi0 = W_ih + (size_t)n * 256;
      const float* wi1 = W_ih + (size_t)(n + 256) * 256;
      const float* wi2 = W_ih + (size_t)(n + 512) * 256;
      float i0 = 0.f, i1 = 0.f, i2 = 0.f;
#pragma unroll 4
      for (int k = 0; k < 256; ++k) {
        float sv = sT[k * 256 + tid];
        i0 = fmaf(sv, wi0[k], i0);
        i1 = fmaf(sv, wi1[k], i1);
        i2 = fmaf(sv, wi2[k], i2);
      }
      i0 += b_ih[n]; i1 += b_ih[n + 256]; i2 += b_ih[n + 512];
      float rr = 1.0f / (1.0f + expf(-(i0 + gh0)));
      float zz = 1.0f / (1.0f + expf(-(i1 + gh1)));
      float nn2 = tanhf(i2 + rr * gh2);
      float ho = hTc[n * 256 + tid];
      hnT[n * 256 + tid] = (1.0f - zz) * nn2 + zz * ho;
    }
    // row: c (s-part reduction + stored h-part)
    {
      float pc = sT[tid * 256 + b] * W_u[tid];
      pc = waveRed(pc);
      if ((tid & 63) == 0) red4[tid >> 6][0] = pc;
    }
    __syncthreads();
    if (tid == 0) {
      float cs = red4[0][0] + red4[1][0] + red4[2][0] + red4[3][0] + ch_sh + b_u[0];
      c_sh = 1.0f / (1.0f + expf(-cs));
    }
    grid_sync(bar, bar + 1);

    // ---------------- Phase 3 (row-owner) ----------------
    float c = c_sh;
    float omc = 1.0f - c;
    if (tid < 16) p_sh[tid] = c * pn_sh[tid] + omc * p_sh[tid];
    if (tid < 32) r_sh[tid] = c * rn_sh[tid] + omc * r_sh[tid];
    float hg;
    {
      float hnv = hnT[tid * 256 + b];
      hg = c * hnv + omc * hk_old;
      hTn[tid * 256 + b] = hg;
      hrow_sh[tid] = hg;
    }
    __syncthreads();
    // logits_g = [h', r'] @ W_pi^T + b_pi
    {
      float part[16];
      const float* wrow = wpiT + tid * 16;
#pragma unroll
      for (int o = 0; o < 16; ++o) part[o] = hg * wrow[o];
      if (tid < 32) {
        const float* wrow2 = wpiT + (256 + tid) * 16;
        float rv = r_sh[tid];
#pragma unroll
        for (int o = 0; o < 16; ++o) part[o] = fmaf(rv, wrow2[o], part[o]);
      }
#pragma unroll
      for (int o = 0; o < 16; ++o) part[o] = waveRed(part[o]);
      int w = tid >> 6;
      if ((tid & 63) == 0) {
#pragma unroll
        for (int o = 0; o < 16; ++o) red16[w][o] = part[o];
      }
    }
    __syncthreads();
    if (tid < 16)
      logit_sh[tid] = red16[0][tid] + red16[1][tid] + red16[2][tid] + red16[3][tid] + b_pi[tid];
    __syncthreads();
    if (tid == 0) {
      const float* gg = ggum + ((size_t)t * 256 + b) * 16;
      float best = -3.402823466e+38f; int gidx = 0;
      for (int n2 = 0; n2 < 16; ++n2) {
        float v = logit_sh[n2] + gg[n2];
        if (v > best) { best = v; gidx = n2; }
      }
      float mx = logit_sh[0];
      for (int n2 = 1; n2 < 16; ++n2) mx = fmaxf(mx, logit_sh[n2]);
      float se = 0.f;
      for (int n2 = 0; n2 < 16; ++n2) se += expf(logit_sh[n2] - mx);
      misc_sh[0] = logit_sh[gidx] - mx - logf(se);
      gidx_sh = gidx;
    }
    __syncthreads();
    if (tid < 32) {
      float gv = c * task[(size_t)b * 512 + gidx_sh * 32 + tid] + omc * g_sh[tid];
      g_sh[tid] = gv;
      gT[tid * 256 + b] = gv;
      rT[tid * 256 + b] = r_sh[tid];
    }
    __syncthreads();
    if (tid == 0) {
      const float* bx2 = bxv + ((size_t)t * 256 + b) * 2;
      float lb0 = bx2[0], lb1 = bx2[1];
      for (int s2 = 0; s2 < 32; ++s2) {
        float gv = g_sh[s2];
        lb0 = fmaf(gv, W_beta[CONV + s2], lb0);
        lb1 = fmaf(gv, W_beta[LDWB + CONV + s2], lb1);
      }
      const float* bg = bgum + ((size_t)t * 256 + b) * 2;
      int bidx = ((lb1 + bg[1]) > (lb0 + bg[0])) ? 1 : 0;
      float mb = fmaxf(lb0, lb1);
      float seb = expf(lb0 - mb) + expf(lb1 - mb);
      float lpb = (bidx ? lb1 : lb0) - mb - logf(seb);
      misc_sh[1] = (float)bidx;
      misc_sh[2] = misc_sh[0] + lpb;
      brow[b] = (float)bidx;
    }
    __syncthreads();
    // outputs: [p16, r32, h256, g32, b1, lp1]
    {
      size_t base = ((size_t)t * 256 + b) * TOT;
      float v;
      if (tid < 16) v = p_sh[tid];
      else if (tid < 48) v = r_sh[tid - 16];
      else v = hrow_sh[tid - 48];
      out[base + tid] = v;
      int s2 = tid + 256;
      if (s2 < TOT) {
        float v2;
        if (s2 < 304) v2 = hrow_sh[s2 - 48];
        else if (s2 < 336) v2 = g_sh[s2 - 304];
        else if (s2 == 336) v2 = misc_sh[1];
        else v2 = misc_sh[2];
        out[base + s2] = v2;
      }
    }
    grid_sync(bar, bar + 1);
    cur ^= 1;
  }
}

// ------------------------------ host launch --------------------------------
extern "C" void kernel_launch(void* const* d_in, const int* in_sizes, int n_in,
                              void* d_out, int out_size, void* d_ws, size_t ws_size,
                              hipStream_t stream) {
  const float* obs    = (const float*)d_in[0];
  const float* task   = (const float*)d_in[1];
  const float* hx0    = (const float*)d_in[2];
  const float* W_ih   = (const float*)d_in[3];
  const float* W_hh   = (const float*)d_in[4];
  const float* b_ih   = (const float*)d_in[5];
  const float* b_hh   = (const float*)d_in[6];
  const float* W_f    = (const float*)d_in[7];
  const float* b_f    = (const float*)d_in[8];
  const float* W_u    = (const float*)d_in[9];
  const float* b_u    = (const float*)d_in[10];
  const float* W_s    = (const float*)d_in[11];
  const float* b_s    = (const float*)d_in[12];
  const float* W_pi   = (const float*)d_in[13];
  const float* b_pi   = (const float*)d_in[14];
  const float* W_beta = (const float*)d_in[15];
  const float* b_beta = (const float*)d_in[16];

  char* ws = (char*)d_ws;
  size_t off = 0;
  auto take = [&](size_t bytes) {
    size_t r = off;
    off += (bytes + 255) & ~(size_t)255;
    return r;
  };
  size_t off_bar  = take(256);
  size_t off_wpiT = take((size_t)288 * 16 * 4);
  size_t off_ggum = take((size_t)T_STEPS * B_ROWS * N_DIM * 4);
  size_t off_bgum = take((size_t)T_STEPS * B_ROWS * 2 * 4);
  size_t off_hT   = take((size_t)2 * 65536 * 4);
  size_t off_sT   = take((size_t)65536 * 4);
  size_t off_hnT  = take((size_t)65536 * 4);
  size_t off_rT   = take((size_t)8192 * 4);
  size_t off_gT   = take((size_t)8192 * 4);
  size_t off_brow = take((size_t)256 * 4);
  size_t off_bx   = take((size_t)T_STEPS * B_ROWS * 2 * 4);
  size_t off_C1T  = take((size_t)T_STEPS * B_ROWS * 256 * 4);
  if (off > ws_size) return;  // insufficient workspace -> fail loudly (poison output)

  unsigned* bar  = (unsigned*)(ws + off_bar);
  float* wpiT    = (float*)(ws + off_wpiT);
  float* ggum    = (float*)(ws + off_ggum);
  float* bgum    = (float*)(ws + off_bgum);
  float* hT      = (float*)(ws + off_hT);
  float* sT      = (float*)(ws + off_sT);
  float* hnT     = (float*)(ws + off_hnT);
  float* rT      = (float*)(ws + off_rT);
  float* gT      = (float*)(ws + off_gT);
  float* brow    = (float*)(ws + off_brow);
  float* bxv     = (float*)(ws + off_bx);
  float* C1T     = (float*)(ws + off_C1T);

  hipMemsetAsync(ws + off_bar, 0, 256, stream);
  hipLaunchKernelGGL(prep_k, dim3(18), dim3(256), 0, stream, W_pi, wpiT);
  hipLaunchKernelGGL(rng_k, dim3(2304), dim3(256), 0, stream, ggum, bgum);
  hipLaunchKernelGGL(init_k, dim3(321), dim3(256), 0, stream, hx0, hT, rT, gT, brow);
  hipLaunchKernelGGL(gemm1_k, dim3(2048), dim3(256), 0, stream, obs, W_f, b_f, C1T);
  hipLaunchKernelGGL(bx_k, dim3(32768), dim3(256), 0, stream, obs, W_beta, b_beta, bxv);
  hipLaunchKernelGGL(seq_k, dim3(256), dim3(256), 0, stream,
                     hx0, task, W_f, W_ih, W_hh, b_ih, b_hh, W_u, b_u, W_s, b_s, b_pi,
                     W_beta, C1T, bxv, wpiT, ggum, bgum,
                     hT, sT, hnT, rT, gT, brow, bar, (float*)d_out);
}